// Round 10
// baseline (731.182 us; speedup 1.0000x reference)
//
#include <hip/hip_runtime.h>

typedef __attribute__((ext_vector_type(8))) short bf16x8;
typedef __attribute__((ext_vector_type(4))) short bf16x4;
typedef __attribute__((ext_vector_type(4))) float f32x4;

#define BATCH 2
#define CH    512
#define NPIX  4096

__device__ __forceinline__ unsigned short f2b(float f) {
    unsigned int u; __builtin_memcpy(&u, &f, 4);
    u = u + 0x7FFFu + ((u >> 16) & 1u);   // RNE
    return (unsigned short)(u >> 16);
}

// ---------------------------------------------------------------- fp32 -> bf16 weight convert
__global__ __launch_bounds__(256) void convert_kernel(
    const float* __restrict__ qkv_w, const float* __restrict__ proj_w,
    unsigned short* __restrict__ wbf)
{
    int i = blockIdx.x * 256 + threadIdx.x;            // grid covers 1048576
    float v = (i < 786432) ? qkv_w[i] : proj_w[i - 786432];
    wbf[i] = f2b(v);
}

// ---------------------------------------------------------------- GN stats
__global__ __launch_bounds__(256) void stats_kernel(
    const float* __restrict__ x, float* __restrict__ stats)
{
    int bg = blockIdx.x;           // 64 blocks: b*32+g
    int b = bg >> 5, g = bg & 31;
    const float* xp = x + ((size_t)b * CH + (size_t)g * 16) * NPIX;
    float s = 0.f, ss = 0.f;
    for (int i = threadIdx.x; i < 16 * NPIX; i += 256) {
        float v = xp[i]; s += v; ss += v * v;
    }
    for (int off = 32; off; off >>= 1) {
        s  += __shfl_down(s,  off, 64);
        ss += __shfl_down(ss, off, 64);
    }
    __shared__ float red[2][4];
    int wv = threadIdx.x >> 6;
    if ((threadIdx.x & 63) == 0) { red[0][wv] = s; red[1][wv] = ss; }
    __syncthreads();
    if (threadIdx.x == 0) {
        s  = red[0][0] + red[0][1] + red[0][2] + red[0][3];
        ss = red[1][0] + red[1][1] + red[1][2] + red[1][3];
        const float inv = 1.f / (16 * NPIX);
        float mean = s * inv;
        float var  = ss * inv - mean * mean;
        stats[bg * 2 + 0] = mean;
        stats[bg * 2 + 1] = rsqrtf(var + 1e-6f);
    }
}

// ---------------------------------------------------------------- K/V GEMM
// block = 32 pixels x ALL 1024 outputs (halves weight traffic vs 16-pixel tiles)
__global__ __launch_bounds__(256) void kv_kernel(
    const float* __restrict__ x,
    const unsigned short* __restrict__ wbf,  // bf16 qkv_w [1536][512]
    const float* __restrict__ bias,
    const float* __restrict__ gamma,
    const float* __restrict__ beta,
    const float* __restrict__ stats,
    unsigned short* __restrict__ K,          // [b][n][c]
    unsigned short* __restrict__ V)          // [b][c][n]
{
    __shared__ unsigned short hn[32][520];
    int b  = blockIdx.y;
    int m0 = blockIdx.x * 32;
    int tid = threadIdx.x;
    {   // stage hn: p = tid&31 (pixel), cg = tid>>5 (channel slot, 8 wide)
        const float* xb = x + (size_t)b * CH * NPIX;
        const float* st = stats + b * 64;
        int p = tid & 31, cg = tid >> 5;
        for (int c0 = 0; c0 < CH; c0 += 8) {
            int c = c0 + cg;
            float mean = st[(c >> 4) * 2 + 0];
            float rstd = st[(c >> 4) * 2 + 1];
            float ga = gamma[c] * rstd;
            float be = beta[c] - mean * ga;
            hn[p][c] = f2b(xb[(size_t)c * NPIX + m0 + p] * ga + be);
        }
    }
    __syncthreads();

    int wv = tid >> 6, lane = tid & 63;
    int ln = lane & 15, quad = lane >> 4;
    #pragma unroll
    for (int nt = 0; nt < 16; nt++) {
        int o = nt * 64 + wv * 16 + ln;            // [0, 1024)
        const unsigned short* bp = wbf + (size_t)(512 + o) * CH + quad * 8;
        float bi = bias[512 + o];
        #pragma unroll
        for (int qt = 0; qt < 2; qt++) {
            f32x4 acc = {0.f, 0.f, 0.f, 0.f};
            #pragma unroll
            for (int k = 0; k < CH; k += 32) {
                bf16x8 a  = *(const bf16x8*)(&hn[qt * 16 + ln][quad * 8 + k]);
                bf16x8 bb = *(const bf16x8*)(bp + k);
                acc = __builtin_amdgcn_mfma_f32_16x16x32_bf16(a, bb, acc, 0, 0, 0);
            }
            int m = m0 + qt * 16 + quad * 4;
            if (o < 512) {
                #pragma unroll
                for (int r = 0; r < 4; r++)
                    K[((size_t)b * NPIX + m + r) * CH + o] = f2b(acc[r] + bi);
            } else {
                bf16x4 pk;
                #pragma unroll
                for (int r = 0; r < 4; r++) pk[r] = f2b(acc[r] + bi);
                *(bf16x4*)(V + ((size_t)b * CH + o - 512) * NPIX + m) = pk;
            }
        }
    }
}

// ---------------------------------------------------------------- attention + proj
// 512 threads = 8 waves; 32 queries/block; 64-key tiles.
// LDS: region A = hn (prologue) -> Sbuf+Pbuf (flash) -> ao (epilogue); region B = qls.
// ~67 KB total -> 2 blocks/CU.
__global__ __launch_bounds__(512, 4) void attnproj_kernel(
    const float* __restrict__ x,
    const unsigned short* __restrict__ qw,   // bf16 qkv_w rows [0,512)
    const float* __restrict__ qb,
    const float* __restrict__ gamma,
    const float* __restrict__ beta,
    const float* __restrict__ stats,
    const unsigned short* __restrict__ Kg,
    const unsigned short* __restrict__ Vg,
    const unsigned short* __restrict__ pw,   // bf16 proj_w [512][512]
    const float* __restrict__ pb,
    float* __restrict__ out)
{
    __shared__ unsigned short smem[2 * 32 * 520];   // 66560 B
    unsigned short (*hn)[520]  = (unsigned short(*)[520])smem;              // region A
    unsigned short (*qls)[520] = (unsigned short(*)[520])(smem + 32 * 520); // region B
    float (*Sbuf)[68]          = (float(*)[68])smem;                        // A[0, 8704)
    unsigned short (*Pbuf)[72] = (unsigned short(*)[72])((char*)smem + 8704); // A[8704, 13312)
    __shared__ float mbuf[32], lbuf[32], abuf[32];

    int b  = blockIdx.y;
    int q0 = blockIdx.x * 32;
    int tid = threadIdx.x;
    int wv = tid >> 6, lane = tid & 63, ln = lane & 15, quad = lane >> 4;
    const float* xb = x + (size_t)b * CH * NPIX;
    const unsigned short* K = Kg + (size_t)b * NPIX * CH;
    const unsigned short* V = Vg + (size_t)b * CH * NPIX;

    {   // stage hn: p = tid&31 (pixel), cg = tid>>5 (channel slot, 16 wide)
        const float* st = stats + b * 64;
        int p = tid & 31, cg = tid >> 5;
        for (int c0 = 0; c0 < CH; c0 += 16) {
            int c = c0 + cg;
            float mean = st[(c >> 4) * 2 + 0];
            float rstd = st[(c >> 4) * 2 + 1];
            float ga = gamma[c] * rstd;
            float be = beta[c] - mean * ga;
            hn[p][c] = f2b(xb[(size_t)c * NPIX + q0 + p] * ga + be);
        }
    }
    if (tid < 32) { mbuf[tid] = -1e30f; lbuf[tid] = 0.f; }
    __syncthreads();

    // ---- Phase Q: q[32][512]; wave wv computes channels [wv*64,+64)
    #pragma unroll
    for (int nt = 0; nt < 4; nt++) {
        int o = wv * 64 + nt * 16 + ln;
        const unsigned short* bp = qw + (size_t)o * CH + quad * 8;
        #pragma unroll
        for (int qt = 0; qt < 2; qt++) {
            f32x4 acc = {0.f, 0.f, 0.f, 0.f};
            #pragma unroll
            for (int k = 0; k < CH; k += 32) {
                bf16x8 a  = *(const bf16x8*)(&hn[qt * 16 + ln][quad * 8 + k]);
                bf16x8 bb = *(const bf16x8*)(bp + k);
                acc = __builtin_amdgcn_mfma_f32_16x16x32_bf16(a, bb, acc, 0, 0, 0);
            }
            float bi = qb[o];
            const float scale = 0.04419417382415922f;  // 512^-0.5
            #pragma unroll
            for (int r = 0; r < 4; r++)
                qls[qt * 16 + quad * 4 + r][o] = f2b((acc[r] + bi) * scale);
        }
    }
    __syncthreads();   // hn dead from here until ao write; S/P take over region A

    // ---- preload q fragments for this wave's S q-subtile
    int qs = wv >> 2, ks = wv & 3;
    bf16x8 qf[16];
    #pragma unroll
    for (int kt = 0; kt < 16; kt++)
        qf[kt] = *(const bf16x8*)(&qls[qs * 16 + ln][quad * 8 + kt * 32]);

    f32x4 O[2][4];   // [qt][ct], D[m=channel][n=query]
    #pragma unroll
    for (int qt = 0; qt < 2; qt++)
        #pragma unroll
        for (int ct = 0; ct < 4; ct++) O[qt][ct] = (f32x4){0.f, 0.f, 0.f, 0.f};

    int c0 = wv * 64;

    // ---- flash loop over 64-key tiles
    for (int kb = 0; kb < NPIX; kb += 64) {
        // S: queries [qs*16,+16) x keys [kb+ks*16,+16)
        f32x4 S = {0.f, 0.f, 0.f, 0.f};
        const unsigned short* kp = K + (size_t)(kb + ks * 16 + ln) * CH + quad * 8;
        #pragma unroll
        for (int kt = 0; kt < 16; kt++) {
            bf16x8 kf = *(const bf16x8*)(kp + kt * 32);
            S = __builtin_amdgcn_mfma_f32_16x16x32_bf16(qf[kt], kf, S, 0, 0, 0);
        }
        #pragma unroll
        for (int r = 0; r < 4; r++) Sbuf[qs * 16 + quad * 4 + r][ks * 16 + ln] = S[r];
        __syncthreads();

        {   // online softmax: row r (query) by 16 threads, 4 keys each
            int r = tid >> 4, j = tid & 15;
            float v0 = Sbuf[r][j * 4 + 0], v1 = Sbuf[r][j * 4 + 1];
            float v2 = Sbuf[r][j * 4 + 2], v3 = Sbuf[r][j * 4 + 3];
            float mx = fmaxf(fmaxf(v0, v1), fmaxf(v2, v3));
            #pragma unroll
            for (int off = 1; off < 16; off <<= 1) mx = fmaxf(mx, __shfl_xor(mx, off, 64));
            float mprev = mbuf[r];
            float mnew  = fmaxf(mprev, mx);
            float alpha = __expf(mprev - mnew);
            float e0 = __expf(v0 - mnew), e1 = __expf(v1 - mnew);
            float e2 = __expf(v2 - mnew), e3 = __expf(v3 - mnew);
            bf16x4 pk = { (short)f2b(e0), (short)f2b(e1), (short)f2b(e2), (short)f2b(e3) };
            *(bf16x4*)(&Pbuf[r][j * 4]) = pk;
            float sum = e0 + e1 + e2 + e3;
            #pragma unroll
            for (int off = 1; off < 16; off <<= 1) sum += __shfl_xor(sum, off, 64);
            if (j == 0) { mbuf[r] = mnew; lbuf[r] = lbuf[r] * alpha + sum; abuf[r] = alpha; }
        }
        __syncthreads();

        // PV: A=v[channel][key], B=P[query][key]; D[channel][query]
        const unsigned short* vp = V + (size_t)(c0 + ln) * NPIX + kb + quad * 8;
        bf16x8 vf[4][2];
        #pragma unroll
        for (int ct = 0; ct < 4; ct++)
            #pragma unroll
            for (int half = 0; half < 2; half++)
                vf[ct][half] = *(const bf16x8*)(vp + (size_t)ct * 16 * NPIX + half * 32);
        #pragma unroll
        for (int qt = 0; qt < 2; qt++) {
            float al = abuf[qt * 16 + ln];
            #pragma unroll
            for (int ct = 0; ct < 4; ct++) {
                #pragma unroll
                for (int r = 0; r < 4; r++) O[qt][ct][r] *= al;
            }
            #pragma unroll
            for (int half = 0; half < 2; half++) {
                bf16x8 pf = *(const bf16x8*)(&Pbuf[qt * 16 + ln][half * 32 + quad * 8]);
                #pragma unroll
                for (int ct = 0; ct < 4; ct++)
                    O[qt][ct] = __builtin_amdgcn_mfma_f32_16x16x32_bf16(vf[ct][half], pf, O[qt][ct], 0, 0, 0);
            }
        }
    }
    __syncthreads();   // all waves done with S/P; region A becomes ao

    // ---- ao[query][channel] into hn (region A)
    #pragma unroll
    for (int qt = 0; qt < 2; qt++) {
        float linv = 1.f / lbuf[qt * 16 + ln];
        #pragma unroll
        for (int ct = 0; ct < 4; ct++) {
            #pragma unroll
            for (int r = 0; r < 4; r++)
                hn[qt * 16 + ln][c0 + ct * 16 + quad * 4 + r] = f2b(O[qt][ct][r] * linv);
        }
    }
    __syncthreads();

    // ---- Phase proj: out channels [wv*64,+64) + bias + residual (fp32)
    #pragma unroll
    for (int nt = 0; nt < 4; nt++) {
        int o = wv * 64 + nt * 16 + ln;
        const unsigned short* bp = pw + (size_t)o * CH + quad * 8;
        float bi = pb[o];
        #pragma unroll
        for (int qt = 0; qt < 2; qt++) {
            f32x4 acc = {0.f, 0.f, 0.f, 0.f};
            #pragma unroll
            for (int k = 0; k < CH; k += 32) {
                bf16x8 a  = *(const bf16x8*)(&hn[qt * 16 + ln][quad * 8 + k]);
                bf16x8 bb = *(const bf16x8*)(bp + k);
                acc = __builtin_amdgcn_mfma_f32_16x16x32_bf16(a, bb, acc, 0, 0, 0);
            }
            size_t base = ((size_t)b * CH + o) * NPIX + q0 + qt * 16 + quad * 4;
            f32x4 xin = *(const f32x4*)(x + base);
            f32x4 o4;
            #pragma unroll
            for (int r = 0; r < 4; r++) o4[r] = xin[r] + acc[r] + bi;
            *(f32x4*)(out + base) = o4;
        }
    }
}

// ----------------------------------------------------------------
extern "C" void kernel_launch(void* const* d_in, const int* in_sizes, int n_in,
                              void* d_out, int out_size, void* d_ws, size_t ws_size,
                              hipStream_t stream)
{
    const float* x      = (const float*)d_in[0];
    const float* gn_g   = (const float*)d_in[1];
    const float* gn_b   = (const float*)d_in[2];
    const float* qkv_w  = (const float*)d_in[3];
    const float* qkv_b  = (const float*)d_in[4];
    const float* proj_w = (const float*)d_in[5];
    const float* proj_b = (const float*)d_in[6];
    float* out = (float*)d_out;

    // Workspace: K 8MB | V 8MB | weights-bf16 2MB | stats 512B
    unsigned short* ws  = (unsigned short*)d_ws;
    unsigned short* Kb  = ws;                         // [2][4096][512] bf16
    unsigned short* Vb  = ws + 4u * 1024 * 1024;      // [2][512][4096] bf16
    unsigned short* wbf = ws + 8u * 1024 * 1024;      // qkv_w | proj_w, bf16
    unsigned short* wq  = wbf;
    unsigned short* wp  = wbf + 786432;
    float* stats = (float*)(ws + 9u * 1024 * 1024 + 256u * 1024);

    convert_kernel<<<dim3(1048576 / 256), 256, 0, stream>>>(qkv_w, proj_w, wbf);
    stats_kernel  <<<dim3(64), 256, 0, stream>>>(x, stats);
    kv_kernel     <<<dim3(NPIX / 32, BATCH), 256, 0, stream>>>(
        x, wbf, qkv_b, gn_g, gn_b, stats, Kb, Vb);
    attnproj_kernel<<<dim3(NPIX / 32, BATCH), 512, 0, stream>>>(
        x, wq, qkv_b, gn_g, gn_b, stats, Kb, Vb, wp, proj_b, out);
}

// Round 11
// 617.264 us; speedup vs baseline: 1.1846x; 1.1846x over previous
//
#include <hip/hip_runtime.h>

typedef __attribute__((ext_vector_type(8))) short bf16x8;
typedef __attribute__((ext_vector_type(4))) short bf16x4;
typedef __attribute__((ext_vector_type(4))) float f32x4;

#define BATCH 2
#define CH    512
#define NPIX  4096

__device__ __forceinline__ unsigned short f2b(float f) {
    unsigned int u; __builtin_memcpy(&u, &f, 4);
    u = u + 0x7FFFu + ((u >> 16) & 1u);   // RNE
    return (unsigned short)(u >> 16);
}

// ---------------------------------------------------------------- fp32 -> bf16 weight convert
__global__ __launch_bounds__(256) void convert_kernel(
    const float* __restrict__ qkv_w, const float* __restrict__ proj_w,
    unsigned short* __restrict__ wbf)
{
    int i = blockIdx.x * 256 + threadIdx.x;            // grid covers 1048576
    float v = (i < 786432) ? qkv_w[i] : proj_w[i - 786432];
    wbf[i] = f2b(v);
}

// ---------------------------------------------------------------- GN stats
__global__ __launch_bounds__(256) void stats_kernel(
    const float* __restrict__ x, float* __restrict__ stats)
{
    int bg = blockIdx.x;           // 64 blocks: b*32+g
    int b = bg >> 5, g = bg & 31;
    const float* xp = x + ((size_t)b * CH + (size_t)g * 16) * NPIX;
    float s = 0.f, ss = 0.f;
    for (int i = threadIdx.x; i < 16 * NPIX; i += 256) {
        float v = xp[i]; s += v; ss += v * v;
    }
    for (int off = 32; off; off >>= 1) {
        s  += __shfl_down(s,  off, 64);
        ss += __shfl_down(ss, off, 64);
    }
    __shared__ float red[2][4];
    int wv = threadIdx.x >> 6;
    if ((threadIdx.x & 63) == 0) { red[0][wv] = s; red[1][wv] = ss; }
    __syncthreads();
    if (threadIdx.x == 0) {
        s  = red[0][0] + red[0][1] + red[0][2] + red[0][3];
        ss = red[1][0] + red[1][1] + red[1][2] + red[1][3];
        const float inv = 1.f / (16 * NPIX);
        float mean = s * inv;
        float var  = ss * inv - mean * mean;
        stats[bg * 2 + 0] = mean;
        stats[bg * 2 + 1] = rsqrtf(var + 1e-6f);
    }
}

// ---------------------------------------------------------------- K/V GEMM
// block = 32 pixels x ALL 1024 outputs; weight frags batch-loaded, shared across qt
__global__ __launch_bounds__(256) void kv_kernel(
    const float* __restrict__ x,
    const unsigned short* __restrict__ wbf,  // bf16 qkv_w [1536][512]
    const float* __restrict__ bias,
    const float* __restrict__ gamma,
    const float* __restrict__ beta,
    const float* __restrict__ stats,
    unsigned short* __restrict__ K,          // [b][n][c]
    unsigned short* __restrict__ V)          // [b][c][n]
{
    __shared__ unsigned short hn[32][520];
    int b  = blockIdx.y;
    int m0 = blockIdx.x * 32;
    int tid = threadIdx.x;
    {   // stage hn: p = tid&31 (pixel), cg = tid>>5 (channel slot, 8 wide)
        const float* xb = x + (size_t)b * CH * NPIX;
        const float* st = stats + b * 64;
        int p = tid & 31, cg = tid >> 5;
        for (int c0 = 0; c0 < CH; c0 += 8) {
            int c = c0 + cg;
            float mean = st[(c >> 4) * 2 + 0];
            float rstd = st[(c >> 4) * 2 + 1];
            float ga = gamma[c] * rstd;
            float be = beta[c] - mean * ga;
            hn[p][c] = f2b(xb[(size_t)c * NPIX + m0 + p] * ga + be);
        }
    }
    __syncthreads();

    int wv = tid >> 6, lane = tid & 63;
    int ln = lane & 15, quad = lane >> 4;
    #pragma unroll
    for (int nt = 0; nt < 16; nt++) {
        int o = nt * 64 + wv * 16 + ln;            // [0, 1024)
        const unsigned short* bp = wbf + (size_t)(512 + o) * CH + quad * 8;
        bf16x8 wf[16];
        #pragma unroll
        for (int k = 0; k < 16; k++) wf[k] = *(const bf16x8*)(bp + k * 32);
        float bi = bias[512 + o];
        #pragma unroll
        for (int qt = 0; qt < 2; qt++) {
            f32x4 acc = {0.f, 0.f, 0.f, 0.f};
            #pragma unroll
            for (int k = 0; k < 16; k++) {
                bf16x8 a = *(const bf16x8*)(&hn[qt * 16 + ln][quad * 8 + k * 32]);
                acc = __builtin_amdgcn_mfma_f32_16x16x32_bf16(a, wf[k], acc, 0, 0, 0);
            }
            int m = m0 + qt * 16 + quad * 4;
            if (o < 512) {
                #pragma unroll
                for (int r = 0; r < 4; r++)
                    K[((size_t)b * NPIX + m + r) * CH + o] = f2b(acc[r] + bi);
            } else {
                bf16x4 pk;
                #pragma unroll
                for (int r = 0; r < 4; r++) pk[r] = f2b(acc[r] + bi);
                *(bf16x4*)(V + ((size_t)b * CH + o - 512) * NPIX + m) = pk;
            }
        }
    }
}

// ---------------------------------------------------------------- attention + proj
// 512 threads = 8 waves; 32 queries/block; 64-key tiles; batched fragment loads.
__global__ __launch_bounds__(512, 2) void attnproj_kernel(
    const float* __restrict__ x,
    const unsigned short* __restrict__ qw,   // bf16 qkv_w rows [0,512)
    const float* __restrict__ qb,
    const float* __restrict__ gamma,
    const float* __restrict__ beta,
    const float* __restrict__ stats,
    const unsigned short* __restrict__ Kg,
    const unsigned short* __restrict__ Vg,
    const unsigned short* __restrict__ pw,   // bf16 proj_w [512][512]
    const float* __restrict__ pb,
    float* __restrict__ out)
{
    __shared__ unsigned short smem[2 * 32 * 520];   // 66560 B
    unsigned short (*hn)[520]  = (unsigned short(*)[520])smem;              // region A
    unsigned short (*qls)[520] = (unsigned short(*)[520])(smem + 32 * 520); // region B
    float (*Sbuf)[68]          = (float(*)[68])smem;                        // A[0, 8704)
    unsigned short (*Pbuf)[72] = (unsigned short(*)[72])((char*)smem + 8704); // A[8704, 13312)
    __shared__ float mbuf[32], lbuf[32], abuf[32];

    int b  = blockIdx.y;
    int q0 = blockIdx.x * 32;
    int tid = threadIdx.x;
    int wv = tid >> 6, lane = tid & 63, ln = lane & 15, quad = lane >> 4;
    const float* xb = x + (size_t)b * CH * NPIX;
    const unsigned short* K = Kg + (size_t)b * NPIX * CH;
    const unsigned short* V = Vg + (size_t)b * CH * NPIX;

    {   // stage hn: p = tid&31 (pixel), cg = tid>>5 (channel slot, 16 wide)
        const float* st = stats + b * 64;
        int p = tid & 31, cg = tid >> 5;
        for (int c0 = 0; c0 < CH; c0 += 16) {
            int c = c0 + cg;
            float mean = st[(c >> 4) * 2 + 0];
            float rstd = st[(c >> 4) * 2 + 1];
            float ga = gamma[c] * rstd;
            float be = beta[c] - mean * ga;
            hn[p][c] = f2b(xb[(size_t)c * NPIX + q0 + p] * ga + be);
        }
    }
    if (tid < 32) { mbuf[tid] = -1e30f; lbuf[tid] = 0.f; }
    __syncthreads();

    // ---- Phase Q: q[32][512]; wave wv computes channels [wv*64,+64)
    #pragma unroll
    for (int nt = 0; nt < 4; nt++) {
        int o = wv * 64 + nt * 16 + ln;
        const unsigned short* bp = qw + (size_t)o * CH + quad * 8;
        bf16x8 wf[16];
        #pragma unroll
        for (int k = 0; k < 16; k++) wf[k] = *(const bf16x8*)(bp + k * 32);
        float bi = qb[o];
        const float scale = 0.04419417382415922f;  // 512^-0.5
        #pragma unroll
        for (int qt = 0; qt < 2; qt++) {
            f32x4 acc = {0.f, 0.f, 0.f, 0.f};
            #pragma unroll
            for (int k = 0; k < 16; k++) {
                bf16x8 a = *(const bf16x8*)(&hn[qt * 16 + ln][quad * 8 + k * 32]);
                acc = __builtin_amdgcn_mfma_f32_16x16x32_bf16(a, wf[k], acc, 0, 0, 0);
            }
            #pragma unroll
            for (int r = 0; r < 4; r++)
                qls[qt * 16 + quad * 4 + r][o] = f2b((acc[r] + bi) * scale);
        }
    }
    __syncthreads();   // hn dead from here until ao write; S/P take over region A

    // ---- preload q fragments for this wave's S q-subtile
    int qs = wv >> 2, ks = wv & 3;
    bf16x8 qf[16];
    #pragma unroll
    for (int kt = 0; kt < 16; kt++)
        qf[kt] = *(const bf16x8*)(&qls[qs * 16 + ln][quad * 8 + kt * 32]);

    f32x4 O[2][4];   // [qt][ct], D[m=channel][n=query]
    #pragma unroll
    for (int qt = 0; qt < 2; qt++)
        #pragma unroll
        for (int ct = 0; ct < 4; ct++) O[qt][ct] = (f32x4){0.f, 0.f, 0.f, 0.f};

    int c0 = wv * 64;

    // ---- flash loop over 64-key tiles
    for (int kb = 0; kb < NPIX; kb += 64) {
        // S: queries [qs*16,+16) x keys [kb+ks*16,+16).
        // Batch ALL 16 K-frag loads into one vmcnt window (16 KB/wave in flight),
        // then the MFMA chain — removes the per-load latency chain.
        const unsigned short* kp = K + (size_t)(kb + ks * 16 + ln) * CH + quad * 8;
        bf16x8 kf[16];
        #pragma unroll
        for (int kt = 0; kt < 16; kt++) kf[kt] = *(const bf16x8*)(kp + kt * 32);
        f32x4 S = {0.f, 0.f, 0.f, 0.f};
        #pragma unroll
        for (int kt = 0; kt < 16; kt++)
            S = __builtin_amdgcn_mfma_f32_16x16x32_bf16(qf[kt], kf[kt], S, 0, 0, 0);
        #pragma unroll
        for (int r = 0; r < 4; r++) Sbuf[qs * 16 + quad * 4 + r][ks * 16 + ln] = S[r];
        __syncthreads();

        {   // online softmax: row r (query) by 16 threads, 4 keys each
            int r = tid >> 4, j = tid & 15;
            float v0 = Sbuf[r][j * 4 + 0], v1 = Sbuf[r][j * 4 + 1];
            float v2 = Sbuf[r][j * 4 + 2], v3 = Sbuf[r][j * 4 + 3];
            float mx = fmaxf(fmaxf(v0, v1), fmaxf(v2, v3));
            #pragma unroll
            for (int off = 1; off < 16; off <<= 1) mx = fmaxf(mx, __shfl_xor(mx, off, 64));
            float mprev = mbuf[r];
            float mnew  = fmaxf(mprev, mx);
            float alpha = __expf(mprev - mnew);
            float e0 = __expf(v0 - mnew), e1 = __expf(v1 - mnew);
            float e2 = __expf(v2 - mnew), e3 = __expf(v3 - mnew);
            bf16x4 pk = { (short)f2b(e0), (short)f2b(e1), (short)f2b(e2), (short)f2b(e3) };
            *(bf16x4*)(&Pbuf[r][j * 4]) = pk;
            float sum = e0 + e1 + e2 + e3;
            #pragma unroll
            for (int off = 1; off < 16; off <<= 1) sum += __shfl_xor(sum, off, 64);
            if (j == 0) { mbuf[r] = mnew; lbuf[r] = lbuf[r] * alpha + sum; abuf[r] = alpha; }
        }
        __syncthreads();

        // PV: A=v[channel][key], B=P[query][key]; D[channel][query]
        const unsigned short* vp = V + (size_t)(c0 + ln) * NPIX + kb + quad * 8;
        bf16x8 vf[4][2];
        #pragma unroll
        for (int ct = 0; ct < 4; ct++)
            #pragma unroll
            for (int half = 0; half < 2; half++)
                vf[ct][half] = *(const bf16x8*)(vp + (size_t)ct * 16 * NPIX + half * 32);
        #pragma unroll
        for (int qt = 0; qt < 2; qt++) {
            float al = abuf[qt * 16 + ln];
            #pragma unroll
            for (int ct = 0; ct < 4; ct++) {
                #pragma unroll
                for (int r = 0; r < 4; r++) O[qt][ct][r] *= al;
            }
            #pragma unroll
            for (int half = 0; half < 2; half++) {
                bf16x8 pf = *(const bf16x8*)(&Pbuf[qt * 16 + ln][half * 32 + quad * 8]);
                #pragma unroll
                for (int ct = 0; ct < 4; ct++)
                    O[qt][ct] = __builtin_amdgcn_mfma_f32_16x16x32_bf16(vf[ct][half], pf, O[qt][ct], 0, 0, 0);
            }
        }
    }
    __syncthreads();   // all waves done with S/P; region A becomes ao

    // ---- ao[query][channel] into hn (region A)
    #pragma unroll
    for (int qt = 0; qt < 2; qt++) {
        float linv = 1.f / lbuf[qt * 16 + ln];
        #pragma unroll
        for (int ct = 0; ct < 4; ct++) {
            #pragma unroll
            for (int r = 0; r < 4; r++)
                hn[qt * 16 + ln][c0 + ct * 16 + quad * 4 + r] = f2b(O[qt][ct][r] * linv);
        }
    }
    __syncthreads();

    // ---- Phase proj: out channels [wv*64,+64) + bias + residual (fp32)
    #pragma unroll
    for (int nt = 0; nt < 4; nt++) {
        int o = wv * 64 + nt * 16 + ln;
        const unsigned short* bp = pw + (size_t)o * CH + quad * 8;
        bf16x8 wf[16];
        #pragma unroll
        for (int k = 0; k < 16; k++) wf[k] = *(const bf16x8*)(bp + k * 32);
        float bi = pb[o];
        #pragma unroll
        for (int qt = 0; qt < 2; qt++) {
            f32x4 acc = {0.f, 0.f, 0.f, 0.f};
            #pragma unroll
            for (int k = 0; k < 16; k++) {
                bf16x8 a = *(const bf16x8*)(&hn[qt * 16 + ln][quad * 8 + k * 32]);
                acc = __builtin_amdgcn_mfma_f32_16x16x32_bf16(a, wf[k], acc, 0, 0, 0);
            }
            size_t base = ((size_t)b * CH + o) * NPIX + q0 + qt * 16 + quad * 4;
            f32x4 xin = *(const f32x4*)(x + base);
            f32x4 o4;
            #pragma unroll
            for (int r = 0; r < 4; r++) o4[r] = xin[r] + acc[r] + bi;
            *(f32x4*)(out + base) = o4;
        }
    }
}

// ----------------------------------------------------------------
extern "C" void kernel_launch(void* const* d_in, const int* in_sizes, int n_in,
                              void* d_out, int out_size, void* d_ws, size_t ws_size,
                              hipStream_t stream)
{
    const float* x      = (const float*)d_in[0];
    const float* gn_g   = (const float*)d_in[1];
    const float* gn_b   = (const float*)d_in[2];
    const float* qkv_w  = (const float*)d_in[3];
    const float* qkv_b  = (const float*)d_in[4];
    const float* proj_w = (const float*)d_in[5];
    const float* proj_b = (const float*)d_in[6];
    float* out = (float*)d_out;

    // Workspace: K 8MB | V 8MB | weights-bf16 2MB | stats 512B
    unsigned short* ws  = (unsigned short*)d_ws;
    unsigned short* Kb  = ws;                         // [2][4096][512] bf16
    unsigned short* Vb  = ws + 4u * 1024 * 1024;      // [2][512][4096] bf16
    unsigned short* wbf = ws + 8u * 1024 * 1024;      // qkv_w | proj_w, bf16
    unsigned short* wq  = wbf;
    unsigned short* wp  = wbf + 786432;
    float* stats = (float*)(ws + 9u * 1024 * 1024 + 256u * 1024);

    convert_kernel<<<dim3(1048576 / 256), 256, 0, stream>>>(qkv_w, proj_w, wbf);
    stats_kernel  <<<dim3(64), 256, 0, stream>>>(x, stats);
    kv_kernel     <<<dim3(NPIX / 32, BATCH), 256, 0, stream>>>(
        x, wbf, qkv_b, gn_g, gn_b, stats, Kb, Vb);
    attnproj_kernel<<<dim3(NPIX / 32, BATCH), 512, 0, stream>>>(
        x, wq, qkv_b, gn_g, gn_b, stats, Kb, Vb, wp, proj_b, out);
}